// Round 1
// baseline (227.460 us; speedup 1.0000x reference)
//
#include <hip/hip_runtime.h>
#include <math.h>

namespace {
constexpr int kB   = 32;
constexpr int kIDF = 128;
constexpr int kCDF = 256;
constexpr int kSL  = 24;
constexpr int kQL  = 128 * 128;
constexpr int kThreads = 256;
constexpr int kQPT = 2;                    // q per thread (float2 path)
constexpr int kQPB = kThreads * kQPT;      // 512 q per block

// sourceT[b,i,l] = sum_c W[i,c] * context[b,c,l]
__global__ __launch_bounds__(kThreads) void proj_kernel(
    const float* __restrict__ W, const float* __restrict__ ctx,
    float* __restrict__ sT_out) {
  const int b = blockIdx.x;
  __shared__ float ctxs[kCDF * kSL];
  const float* ctxb = ctx + (size_t)b * kCDF * kSL;
  for (int t = threadIdx.x; t < kCDF * kSL; t += kThreads) ctxs[t] = ctxb[t];
  __syncthreads();
  #pragma unroll
  for (int k = 0; k < (kIDF * kSL) / kThreads; ++k) {
    const int o = threadIdx.x + k * kThreads;
    const int i = o / kSL, l = o % kSL;
    const float* wrow = W + i * kCDF;
    float acc = 0.f;
    #pragma unroll 8
    for (int c = 0; c < kCDF; ++c) acc = fmaf(wrow[c], ctxs[c * kSL + l], acc);
    sT_out[(size_t)b * kIDF * kSL + o] = acc;
  }
}

template <bool FUSED>
__global__ __launch_bounds__(kThreads) void attn_kernel(
    const float* __restrict__ input, const float* __restrict__ sT_in,
    const float* __restrict__ W, const float* __restrict__ ctx,
    const int* __restrict__ mask, float* __restrict__ out_wc,
    float* __restrict__ out_attn) {
  const int b  = blockIdx.y;
  const int q0 = blockIdx.x * kQPB + threadIdx.x * kQPT;
  constexpr int kSTN = kIDF * kSL;
  __shared__ float smem[FUSED ? (kSTN + kCDF * kSL) : kSTN];
  float* sT = smem;
  if (FUSED) {
    // compute sourceT in-block (no workspace available)
    float* ctxs = smem + kSTN;
    const float* ctxb = ctx + (size_t)b * kCDF * kSL;
    for (int t = threadIdx.x; t < kCDF * kSL; t += kThreads) ctxs[t] = ctxb[t];
    __syncthreads();
    for (int k = 0; k < kSTN / kThreads; ++k) {
      const int o = threadIdx.x + k * kThreads;
      const int i = o / kSL, l = o % kSL;
      const float* wrow = W + i * kCDF;
      float acc = 0.f;
      for (int c = 0; c < kCDF; ++c) acc = fmaf(wrow[c], ctxs[c * kSL + l], acc);
      sT[o] = acc;
    }
  } else {
    const float* g = sT_in + (size_t)b * kSTN;
    for (int t = threadIdx.x; t < kSTN; t += kThreads) sT[t] = g[t];
  }
  __syncthreads();

  // mask bit set == position masked with -inf (weight 0)
  unsigned mbits = 0;
  #pragma unroll
  for (int l = 0; l < kSL; ++l) mbits |= (mask[b * kSL + l] ? 1u : 0u) << l;

  float acc0[kSL], acc1[kSL];
  #pragma unroll
  for (int l = 0; l < kSL; ++l) { acc0[l] = 0.f; acc1[l] = 0.f; }

  // attn[b,q,l] = sum_i input[b,i,q] * sT[i,l]
  const float* inb = input + (size_t)b * kIDF * kQL + q0;
  #pragma unroll 2
  for (int i = 0; i < kIDF; ++i) {
    const float2 t = *reinterpret_cast<const float2*>(inb + (size_t)i * kQL);
    #pragma unroll
    for (int l = 0; l < kSL; ++l) {
      const float w = sT[i * kSL + l];
      acc0[l] = fmaf(t.x, w, acc0[l]);
      acc1[l] = fmaf(t.y, w, acc1[l]);
    }
  }

  // masked softmax over l (24)
  {
    float m0 = -INFINITY, m1 = -INFINITY;
    #pragma unroll
    for (int l = 0; l < kSL; ++l)
      if (!((mbits >> l) & 1u)) { m0 = fmaxf(m0, acc0[l]); m1 = fmaxf(m1, acc1[l]); }
    float s0 = 0.f, s1 = 0.f;
    #pragma unroll
    for (int l = 0; l < kSL; ++l) {
      const bool km = (mbits >> l) & 1u;
      const float p0 = km ? 0.f : __expf(acc0[l] - m0);
      const float p1 = km ? 0.f : __expf(acc1[l] - m1);
      acc0[l] = p0; acc1[l] = p1; s0 += p0; s1 += p1;
    }
    const float r0 = 1.f / s0, r1 = 1.f / s1;
    #pragma unroll
    for (int l = 0; l < kSL; ++l) { acc0[l] *= r0; acc1[l] *= r1; }
  }

  // attn_out[b,l,q] (transposed attention map)
  float* oa = out_attn + (size_t)b * kSL * kQL + q0;
  #pragma unroll
  for (int l = 0; l < kSL; ++l)
    *reinterpret_cast<float2*>(oa + (size_t)l * kQL) = make_float2(acc0[l], acc1[l]);

  // weightedContext[b,i,q] = sum_l sT[i,l] * attn[b,q,l]
  float* ow = out_wc + (size_t)b * kIDF * kQL + q0;
  #pragma unroll 2
  for (int i = 0; i < kIDF; ++i) {
    float x = 0.f, y = 0.f;
    #pragma unroll
    for (int l = 0; l < kSL; ++l) {
      const float w = sT[i * kSL + l];
      x = fmaf(w, acc0[l], x);
      y = fmaf(w, acc1[l], y);
    }
    *reinterpret_cast<float2*>(ow + (size_t)i * kQL) = make_float2(x, y);
  }
}
}  // namespace

extern "C" void kernel_launch(void* const* d_in, const int* in_sizes, int n_in,
                              void* d_out, int out_size, void* d_ws, size_t ws_size,
                              hipStream_t stream) {
  const float* input = (const float*)d_in[0];
  const float* ctx   = (const float*)d_in[1];
  const float* W     = (const float*)d_in[2];
  const int*   mask  = (const int*)d_in[3];
  float* out_wc   = (float*)d_out;
  float* out_attn = (float*)d_out + (size_t)kB * kIDF * kQL;

  const size_t st_bytes = (size_t)kB * kIDF * kSL * sizeof(float);
  dim3 grid(kQL / kQPB, kB);
  if (ws_size >= st_bytes) {
    float* sT = (float*)d_ws;
    proj_kernel<<<kB, kThreads, 0, stream>>>(W, ctx, sT);
    attn_kernel<false><<<grid, kThreads, 0, stream>>>(input, sT, W, ctx, mask,
                                                      out_wc, out_attn);
  } else {
    attn_kernel<true><<<grid, kThreads, 0, stream>>>(input, nullptr, W, ctx, mask,
                                                     out_wc, out_attn);
  }
}

// Round 2
// 220.398 us; speedup vs baseline: 1.0320x; 1.0320x over previous
//
#include <hip/hip_runtime.h>
#include <math.h>

namespace {
constexpr int kB   = 32;
constexpr int kIDF = 128;
constexpr int kCDF = 256;
constexpr int kSL  = 24;
constexpr int kQL  = 128 * 128;
constexpr int kThreads = 256;
constexpr int kQPT = 2;                    // q per thread (float2 path)
constexpr int kQPB = kThreads * kQPT;      // 512 q per block

// sourceT[b,i,l] = sum_c W[i,c] * context[b,c,l]
__global__ __launch_bounds__(kThreads) void proj_kernel(
    const float* __restrict__ W, const float* __restrict__ ctx,
    float* __restrict__ sT_out) {
  const int b = blockIdx.x;
  __shared__ float ctxs[kCDF * kSL];
  const float* ctxb = ctx + (size_t)b * kCDF * kSL;
  for (int t = threadIdx.x; t < kCDF * kSL; t += kThreads) ctxs[t] = ctxb[t];
  __syncthreads();
  #pragma unroll
  for (int k = 0; k < (kIDF * kSL) / kThreads; ++k) {
    const int o = threadIdx.x + k * kThreads;
    const int i = o / kSL, l = o % kSL;
    const float* wrow = W + i * kCDF;
    float acc = 0.f;
    #pragma unroll 8
    for (int c = 0; c < kCDF; ++c) acc = fmaf(wrow[c], ctxs[c * kSL + l], acc);
    sT_out[(size_t)b * kIDF * kSL + o] = acc;
  }
}

template <bool FUSED>
__global__ __launch_bounds__(kThreads) void attn_kernel(
    const float* __restrict__ input, const float* __restrict__ sT_in,
    const float* __restrict__ W, const float* __restrict__ ctx,
    const int* __restrict__ mask, float* __restrict__ out_wc,
    float* __restrict__ out_attn) {
  const int b  = blockIdx.y;
  const int q0 = blockIdx.x * kQPB + threadIdx.x * kQPT;
  constexpr int kSTN = kIDF * kSL;
  __shared__ float smem[FUSED ? (kSTN + kCDF * kSL) : kSTN];
  float* sT = smem;
  if (FUSED) {
    // compute sourceT in-block (no workspace available)
    float* ctxs = smem + kSTN;
    const float* ctxb = ctx + (size_t)b * kCDF * kSL;
    for (int t = threadIdx.x; t < kCDF * kSL; t += kThreads) ctxs[t] = ctxb[t];
    __syncthreads();
    for (int k = 0; k < kSTN / kThreads; ++k) {
      const int o = threadIdx.x + k * kThreads;
      const int i = o / kSL, l = o % kSL;
      const float* wrow = W + i * kCDF;
      float acc = 0.f;
      for (int c = 0; c < kCDF; ++c) acc = fmaf(wrow[c], ctxs[c * kSL + l], acc);
      sT[o] = acc;
    }
  } else {
    const float* g = sT_in + (size_t)b * kSTN;
    for (int t = threadIdx.x; t < kSTN; t += kThreads) sT[t] = g[t];
  }
  __syncthreads();

  // mask bit set == position masked with -inf (weight 0)
  unsigned mbits = 0;
  #pragma unroll
  for (int l = 0; l < kSL; ++l) mbits |= (mask[b * kSL + l] ? 1u : 0u) << l;

  float acc0[kSL], acc1[kSL];
  #pragma unroll
  for (int l = 0; l < kSL; ++l) { acc0[l] = 0.f; acc1[l] = 0.f; }

  // attn[b,q,l] = sum_i input[b,i,q] * sT[i,l]
  // 8-deep explicit load staging: 8 outstanding global loads per wave so
  // 16 waves/CU x 8 x 512B = 64KB in flight > Little's-law requirement.
  const float* inb = input + (size_t)b * kIDF * kQL + q0;
  #pragma unroll 1
  for (int ii = 0; ii < kIDF; ii += 8) {
    float2 tbuf[8];
    #pragma unroll
    for (int u = 0; u < 8; ++u)
      tbuf[u] = *reinterpret_cast<const float2*>(inb + (size_t)(ii + u) * kQL);
    #pragma unroll
    for (int u = 0; u < 8; ++u) {
      const float* wrow = &sT[(ii + u) * kSL];
      #pragma unroll
      for (int l = 0; l < kSL; ++l) {
        const float w = wrow[l];
        acc0[l] = fmaf(tbuf[u].x, w, acc0[l]);
        acc1[l] = fmaf(tbuf[u].y, w, acc1[l]);
      }
    }
  }

  // masked softmax over l (24)
  {
    float m0 = -INFINITY, m1 = -INFINITY;
    #pragma unroll
    for (int l = 0; l < kSL; ++l)
      if (!((mbits >> l) & 1u)) { m0 = fmaxf(m0, acc0[l]); m1 = fmaxf(m1, acc1[l]); }
    float s0 = 0.f, s1 = 0.f;
    #pragma unroll
    for (int l = 0; l < kSL; ++l) {
      const bool km = (mbits >> l) & 1u;
      const float p0 = km ? 0.f : __expf(acc0[l] - m0);
      const float p1 = km ? 0.f : __expf(acc1[l] - m1);
      acc0[l] = p0; acc1[l] = p1; s0 += p0; s1 += p1;
    }
    const float r0 = 1.f / s0, r1 = 1.f / s1;
    #pragma unroll
    for (int l = 0; l < kSL; ++l) { acc0[l] *= r0; acc1[l] *= r1; }
  }

  // attn_out[b,l,q] (transposed attention map)
  float* oa = out_attn + (size_t)b * kSL * kQL + q0;
  #pragma unroll
  for (int l = 0; l < kSL; ++l)
    *reinterpret_cast<float2*>(oa + (size_t)l * kQL) = make_float2(acc0[l], acc1[l]);

  // weightedContext[b,i,q] = sum_l sT[i,l] * attn[b,q,l]
  float* ow = out_wc + (size_t)b * kIDF * kQL + q0;
  #pragma unroll 1
  for (int ii = 0; ii < kIDF; ii += 4) {
    float2 o[4];
    #pragma unroll
    for (int u = 0; u < 4; ++u) {
      const float* wrow = &sT[(ii + u) * kSL];
      float x = 0.f, y = 0.f;
      #pragma unroll
      for (int l = 0; l < kSL; ++l) {
        const float w = wrow[l];
        x = fmaf(w, acc0[l], x);
        y = fmaf(w, acc1[l], y);
      }
      o[u] = make_float2(x, y);
    }
    #pragma unroll
    for (int u = 0; u < 4; ++u)
      *reinterpret_cast<float2*>(ow + (size_t)(ii + u) * kQL) = o[u];
  }
}
}  // namespace

extern "C" void kernel_launch(void* const* d_in, const int* in_sizes, int n_in,
                              void* d_out, int out_size, void* d_ws, size_t ws_size,
                              hipStream_t stream) {
  const float* input = (const float*)d_in[0];
  const float* ctx   = (const float*)d_in[1];
  const float* W     = (const float*)d_in[2];
  const int*   mask  = (const int*)d_in[3];
  float* out_wc   = (float*)d_out;
  float* out_attn = (float*)d_out + (size_t)kB * kIDF * kQL;

  const size_t st_bytes = (size_t)kB * kIDF * kSL * sizeof(float);
  dim3 grid(kQL / kQPB, kB);
  if (ws_size >= st_bytes) {
    float* sT = (float*)d_ws;
    proj_kernel<<<kB, kThreads, 0, stream>>>(W, ctx, sT);
    attn_kernel<false><<<grid, kThreads, 0, stream>>>(input, sT, W, ctx, mask,
                                                      out_wc, out_attn);
  } else {
    attn_kernel<true><<<grid, kThreads, 0, stream>>>(input, nullptr, W, ctx, mask,
                                                     out_wc, out_attn);
  }
}

// Round 4
// 169.933 us; speedup vs baseline: 1.3385x; 1.2970x over previous
//
#include <hip/hip_runtime.h>
#include <math.h>

namespace {
constexpr int kB   = 32;
constexpr int kIDF = 128;
constexpr int kCDF = 256;
constexpr int kSL  = 24;
constexpr int kQL  = 128 * 128;
constexpr int kThreads = 256;
constexpr int kQPT = 4;                    // q per thread (float4 path)
constexpr int kQPB = kThreads * kQPT;      // 1024 q per block

typedef float f32x4 __attribute__((ext_vector_type(4)));

// sourceT[b,i,l] = sum_c W[i,c] * context[b,c,l]
__global__ __launch_bounds__(kThreads) void proj_kernel(
    const float* __restrict__ W, const float* __restrict__ ctx,
    float* __restrict__ sT_out) {
  const int b = blockIdx.x;
  __shared__ float ctxs[kCDF * kSL];
  const float* ctxb = ctx + (size_t)b * kCDF * kSL;
  for (int t = threadIdx.x; t < kCDF * kSL; t += kThreads) ctxs[t] = ctxb[t];
  __syncthreads();
  #pragma unroll
  for (int k = 0; k < (kIDF * kSL) / kThreads; ++k) {
    const int o = threadIdx.x + k * kThreads;
    const int i = o / kSL, l = o % kSL;
    const float* wrow = W + i * kCDF;
    float acc = 0.f;
    #pragma unroll 8
    for (int c = 0; c < kCDF; ++c) acc = fmaf(wrow[c], ctxs[c * kSL + l], acc);
    sT_out[(size_t)b * kIDF * kSL + o] = acc;
  }
}

template <bool FUSED>
__global__ __launch_bounds__(kThreads) void attn_kernel(
    const float* __restrict__ input, const float* __restrict__ sT_in,
    const float* __restrict__ W, const float* __restrict__ ctx,
    const int* __restrict__ mask, float* __restrict__ out_wc,
    float* __restrict__ out_attn) {
  const int b  = blockIdx.y;
  const int q0 = blockIdx.x * kQPB + threadIdx.x * kQPT;
  constexpr int kSTN = kIDF * kSL;
  __shared__ float smem[FUSED ? (kSTN + kCDF * kSL) : kSTN];
  float* sT = smem;
  if (FUSED) {
    float* ctxs = smem + kSTN;
    const float* ctxb = ctx + (size_t)b * kCDF * kSL;
    for (int t = threadIdx.x; t < kCDF * kSL; t += kThreads) ctxs[t] = ctxb[t];
    __syncthreads();
    for (int k = 0; k < kSTN / kThreads; ++k) {
      const int o = threadIdx.x + k * kThreads;
      const int i = o / kSL, l = o % kSL;
      const float* wrow = W + i * kCDF;
      float acc = 0.f;
      for (int c = 0; c < kCDF; ++c) acc = fmaf(wrow[c], ctxs[c * kSL + l], acc);
      sT[o] = acc;
    }
  } else {
    const float* g = sT_in + (size_t)b * kSTN;
    for (int t = threadIdx.x; t < kSTN; t += kThreads) sT[t] = g[t];
  }
  __syncthreads();

  // mask bit set == position masked with -inf (weight 0)
  unsigned mbits = 0;
  #pragma unroll
  for (int l = 0; l < kSL; ++l) mbits |= (mask[b * kSL + l] ? 1u : 0u) << l;

  // acc[l] holds scores (later probs) for this thread's 4 q's.
  f32x4 acc[kSL];
  #pragma unroll
  for (int l = 0; l < kSL; ++l) acc[l] = (f32x4)0.f;

  // attn[b,q,l] = sum_i input[b,i,q] * sT[i,l]
  // dwordx4 loads (1KB/wave-instr); ds_read_b128 for sT rows.
  const float* inb = input + (size_t)b * kIDF * kQL + q0;
  #pragma unroll 1
  for (int ii = 0; ii < kIDF; ii += 8) {
    f32x4 t[8];
    #pragma unroll
    for (int u = 0; u < 8; ++u)
      t[u] = *reinterpret_cast<const f32x4*>(inb + (size_t)(ii + u) * kQL);
    #pragma unroll
    for (int u = 0; u < 8; ++u) {
      const float* wrow = &sT[(ii + u) * kSL];
      #pragma unroll
      for (int j = 0; j < kSL / 4; ++j) {
        const f32x4 w = *reinterpret_cast<const f32x4*>(wrow + 4 * j);
        #pragma unroll
        for (int e = 0; e < 4; ++e) {
          #pragma unroll
          for (int c = 0; c < 4; ++c)
            acc[4 * j + e][c] = fmaf(t[u][c], w[e], acc[4 * j + e][c]);
        }
      }
    }
  }

  // masked softmax over l (24), per q-component
  {
    float m[4] = {-INFINITY, -INFINITY, -INFINITY, -INFINITY};
    #pragma unroll
    for (int l = 0; l < kSL; ++l)
      if (!((mbits >> l) & 1u)) {
        #pragma unroll
        for (int c = 0; c < 4; ++c) m[c] = fmaxf(m[c], acc[l][c]);
      }
    float s[4] = {0.f, 0.f, 0.f, 0.f};
    #pragma unroll
    for (int l = 0; l < kSL; ++l) {
      const bool km = (mbits >> l) & 1u;
      #pragma unroll
      for (int c = 0; c < 4; ++c) {
        const float p = km ? 0.f : __expf(acc[l][c] - m[c]);
        acc[l][c] = p;
        s[c] += p;
      }
    }
    float r[4];
    #pragma unroll
    for (int c = 0; c < 4; ++c) r[c] = 1.f / s[c];
    #pragma unroll
    for (int l = 0; l < kSL; ++l) {
      #pragma unroll
      for (int c = 0; c < 4; ++c) acc[l][c] *= r[c];
    }
  }

  // attn_out[b,l,q] — streamed once, nontemporal to avoid evicting input
  float* oa = out_attn + (size_t)b * kSL * kQL + q0;
  #pragma unroll
  for (int l = 0; l < kSL; ++l)
    __builtin_nontemporal_store(acc[l], reinterpret_cast<f32x4*>(oa + (size_t)l * kQL));

  // weightedContext[b,i,q] = sum_l sT[i,l] * attn[b,q,l]
  float* ow = out_wc + (size_t)b * kIDF * kQL + q0;
  #pragma unroll 1
  for (int ii = 0; ii < kIDF; ii += 8) {
    f32x4 res[8];
    #pragma unroll
    for (int u = 0; u < 8; ++u) res[u] = (f32x4)0.f;
    #pragma unroll
    for (int u = 0; u < 8; ++u) {
      const float* wrow = &sT[(ii + u) * kSL];
      #pragma unroll
      for (int j = 0; j < kSL / 4; ++j) {
        const f32x4 w = *reinterpret_cast<const f32x4*>(wrow + 4 * j);
        #pragma unroll
        for (int e = 0; e < 4; ++e) {
          #pragma unroll
          for (int c = 0; c < 4; ++c)
            res[u][c] = fmaf(w[e], acc[4 * j + e][c], res[u][c]);
        }
      }
    }
    #pragma unroll
    for (int u = 0; u < 8; ++u)
      __builtin_nontemporal_store(res[u],
          reinterpret_cast<f32x4*>(ow + (size_t)(ii + u) * kQL));
  }
}
}  // namespace

extern "C" void kernel_launch(void* const* d_in, const int* in_sizes, int n_in,
                              void* d_out, int out_size, void* d_ws, size_t ws_size,
                              hipStream_t stream) {
  const float* input = (const float*)d_in[0];
  const float* ctx   = (const float*)d_in[1];
  const float* W     = (const float*)d_in[2];
  const int*   mask  = (const int*)d_in[3];
  float* out_wc   = (float*)d_out;
  float* out_attn = (float*)d_out + (size_t)kB * kIDF * kQL;

  const size_t st_bytes = (size_t)kB * kIDF * kSL * sizeof(float);
  dim3 grid(kQL / kQPB, kB);
  if (ws_size >= st_bytes) {
    float* sT = (float*)d_ws;
    proj_kernel<<<kB, kThreads, 0, stream>>>(W, ctx, sT);
    attn_kernel<false><<<grid, kThreads, 0, stream>>>(input, sT, W, ctx, mask,
                                                      out_wc, out_attn);
  } else {
    attn_kernel<true><<<grid, kThreads, 0, stream>>>(input, nullptr, W, ctx, mask,
                                                     out_wc, out_attn);
  }
}